// Round 8
// baseline (39.720 us; speedup 1.0000x reference)
//
#include <hip/hip_runtime.h>
#include <hip/hip_bf16.h>
#include <math.h>

// PersistentHomology: out = std(dist, ddof=1) / (mean(dist) + 1e-8) over the
// 8192x8192 Euclidean distance matrix of 8192 fp32 points, D=128.
// S1 = sum(dist) via bf16-MFMA Gram tiles (upper-triangle, 256^2 blocks).
// S2 = sum(dist^2) has a CLOSED FORM: 2N*sum(|x_i|^2) - 2*|sum_i x_i|^2 —
// computed exactly in fp64 (prep partials + deterministic finalize reduce).
// Round 8: 4 K-quarter phases with counted s_waitcnt vmcnt(N) + raw s_barrier
// (never drain to 0 mid-loop), s_setprio around MFMA, sqrt-only epilogue.

#define NPTS   8192
#define DIM    128
#define BT     256                            // block tile
#define NT2    (NPTS / BT)                    // 32 tiles per side
#define NBLK   (NT2 * (NT2 + 1) / 2)          // 528 upper-tri blocks
#define NPREP  (NPTS / 32)                    // 256 prep blocks
#define NTILES (NPTS / 128)                   // fp32 fallback path
#define NTOTSQ (NTILES * NTILES)

typedef __attribute__((ext_vector_type(8))) short short8;   // 8 bf16
typedef __attribute__((ext_vector_type(4))) float f32x4;    // MFMA accumulator

typedef const __attribute__((address_space(1))) void* gas_ptr;
typedef __attribute__((address_space(3))) void* las_ptr;

__device__ __forceinline__ void gload16(const void* g, void* l) {
    // DMA 16B/lane global->LDS; LDS dest = wave-uniform base + lane*16
    __builtin_amdgcn_global_load_lds((gas_ptr)g, (las_ptr)l, 16, 0, 0);
}
__device__ __forceinline__ float fsqrt(float x) {
    return __builtin_amdgcn_sqrtf(x);        // v_sqrt_f32
}

#define VMCNT(n) asm volatile("s_waitcnt vmcnt(" #n ")" ::: "memory")
#define RBAR()   __builtin_amdgcn_s_barrier()

// ---- prep: fp32 -> bf16, fp32 norms, per-block fp32 column-sum partials ----
__global__ __launch_bounds__(256)
void ph_prep(const float* __restrict__ x, ushort* __restrict__ xb,
             float* __restrict__ sq, float* __restrict__ cs_part)
{
    __shared__ float xs[32][129];                  // padded: conflict-free col reads
    const int tid = threadIdx.x;
    const int rw  = tid >> 3;                      // 0..31 row-in-block
    const int row = blockIdx.x * 32 + rw;
    const int seg = tid & 7;                       // 16 elems per thread
    const float4* p = reinterpret_cast<const float4*>(x + (size_t)row * DIM + seg * 16);
    float v[16];
    {
        float4 a = p[0], b = p[1], c = p[2], d = p[3];
        v[0]=a.x; v[1]=a.y; v[2]=a.z; v[3]=a.w;  v[4]=b.x; v[5]=b.y; v[6]=b.z; v[7]=b.w;
        v[8]=c.x; v[9]=c.y; v[10]=c.z; v[11]=c.w; v[12]=d.x; v[13]=d.y; v[14]=d.z; v[15]=d.w;
    }
    float s = 0.f;
    ushort h[16];
#pragma unroll
    for (int j = 0; j < 16; ++j) {
        __hip_bfloat16 hb = __float2bfloat16(v[j]);
        h[j] = *reinterpret_cast<ushort*>(&hb);
        s = fmaf(v[j], v[j], s);
        xs[rw][seg * 16 + j] = v[j];
    }
    short8 o0, o1;
#pragma unroll
    for (int j = 0; j < 8; ++j) { o0[j] = (short)h[j]; o1[j] = (short)h[j+8]; }
    short8* dst = reinterpret_cast<short8*>(xb + (size_t)row * DIM + seg * 16);
    dst[0] = o0; dst[1] = o1;
    s += __shfl_xor(s, 1); s += __shfl_xor(s, 2); s += __shfl_xor(s, 4);
    if (seg == 0) sq[row] = s;
    __syncthreads();
    if (tid < DIM) {                               // column sums over 32 rows
        float c = 0.f;
#pragma unroll 8
        for (int r = 0; r < 32; ++r) c += xs[r][tid];
        cs_part[blockIdx.x * DIM + tid] = c;
    }
}

// ---- main: 256^2-tile, 8-wave, 4-phase counted-vmcnt bf16 MFMA Gram (S1 only) --
// 4 K-quarter buffers per operand (BK=32, 16KB each, 64B rows, linear layout).
__global__ __launch_bounds__(512)
void ph_gram(const ushort* __restrict__ xb, const float* __restrict__ sq,
             double* __restrict__ partials)
{
    const int f   = blockIdx.x;          // 0..NBLK-1
    const int tid = threadIdx.x;

    // decode flat -> (bi, bj), bi <= bj ; T(r) = r*32 - r*(r-1)/2
    int bi = (int)((65.0f - fsqrt((float)(4225 - 8 * f))) * 0.5f);
    while ((bi + 1) * 32 - ((bi + 1) * bi) / 2 <= f) ++bi;
    while (bi * 32 - (bi * (bi - 1)) / 2 > f) --bi;
    const int bj = bi + (f - (bi * 32 - (bi * (bi - 1)) / 2));

    __shared__ ushort Aq[4][BT * 32];    // 4 x 16 KB
    __shared__ ushort Bq[4][BT * 32];    // 4 x 16 KB
    __shared__ double rr[8];

    const int lane = tid & 63;
    const int wv   = tid >> 6;           // wave 0..7
    const int wr2  = wv >> 2;            // 0..1 -> row base *128
    const int wc4  = wv & 3;             // 0..3 -> col base *64

    const char* gA = (const char*)(xb + (size_t)bi * BT * DIM);
    const char* gB = (const char*)(xb + (size_t)bj * BT * DIM);

    // staging: waves 0-3 stage A-quarters, waves 4-7 stage B-quarters.
    // quarter buffer = 16 chunks of 1KB (16 rows x 64B); wave handles 4 chunks.
    const bool  stA  = wv < 4;
    const char* gsrc = stA ? gA : gB;
    const int   c0   = (wv & 3) * 4;
    const int   lrow = lane >> 2;              // 0..15 row within chunk
    const int   lks  = (lane & 3) * 16;        // 16B slot within 64B row

#define STAGE(q)                                                              \
    {                                                                         \
        char* dst_ = stA ? (char*)Aq[q] : (char*)Bq[q];                       \
        _Pragma("unroll")                                                     \
        for (int c = 0; c < 4; ++c) {                                         \
            const int chunk = c0 + c;                                         \
            const int row   = chunk * 16 + lrow;                              \
            const size_t go = (size_t)row * 256 + (q) * 64 + lks;             \
            gload16(gsrc + go, dst_ + chunk * 1024);                          \
        }                                                                     \
    }

    f32x4 acc[8][4];
#pragma unroll
    for (int m = 0; m < 8; ++m)
#pragma unroll
        for (int n = 0; n < 4; ++n) acc[m][n] = (f32x4){0.f, 0.f, 0.f, 0.f};

#define COMPUTE(q)                                                            \
    {                                                                         \
        const int kb = (lane >> 4) * 16;                                      \
        short8 af[8], bfr[4];                                                 \
        _Pragma("unroll")                                                     \
        for (int m = 0; m < 8; ++m) {                                         \
            const int row = wr2 * 128 + m * 16 + (lane & 15);                 \
            af[m] = *reinterpret_cast<const short8*>(                         \
                (const char*)Aq[q] + row * 64 + kb);                          \
        }                                                                     \
        _Pragma("unroll")                                                     \
        for (int n = 0; n < 4; ++n) {                                         \
            const int col = wc4 * 64 + n * 16 + (lane & 15);                  \
            bfr[n] = *reinterpret_cast<const short8*>(                        \
                (const char*)Bq[q] + col * 64 + kb);                          \
        }                                                                     \
        __builtin_amdgcn_s_setprio(1);                                        \
        _Pragma("unroll")                                                     \
        for (int m = 0; m < 8; ++m)                                           \
            _Pragma("unroll")                                                 \
            for (int n = 0; n < 4; ++n)                                       \
                acc[m][n] = __builtin_amdgcn_mfma_f32_16x16x32_bf16(          \
                    af[m], bfr[n], acc[m][n], 0, 0, 0);                       \
        __builtin_amdgcn_s_setprio(0);                                        \
    }

    // ---- counted-vmcnt 4-phase pipeline (prefetch distance 2) ----
    STAGE(0);               // out 4
    STAGE(1);               // out 8
    VMCNT(4); RBAR();       // q0 landed everywhere
    COMPUTE(0);
    STAGE(2);               // out q1+q2 = 8
    VMCNT(4); RBAR();       // q1 landed
    COMPUTE(1);
    STAGE(3);               // out q2+q3 = 8

    // norm loads fly under the remaining compute (8 VMEM insts, drained last)
    const float* sqA = sq + bi * BT + wr2 * 128 + (lane >> 4) * 4;
    const float* sqB = sq + bj * BT + wc4 * 64 + (lane & 15);
    float4 na[4];
    float  nb[4];
#pragma unroll
    for (int m = 0; m < 4; ++m) na[m] = *reinterpret_cast<const float4*>(sqA + m * 32);
#pragma unroll
    for (int n = 0; n < 4; ++n) nb[n] = sqB[n * 16];

    VMCNT(12); RBAR();      // q2 landed (q3 + norms still in flight)
    COMPUTE(2);
    VMCNT(8); RBAR();       // q3 landed (norms still in flight)
    COMPUTE(3);
    VMCNT(0);               // norms landed

    // ---- epilogue: S1 only (S2 is closed-form), wave-uniform diag split ----
    float s1a = 0.f, s1b = 0.f, s1c = 0.f, s1d = 0.f;
    const bool diag = (bi == bj);
    if (!diag) {
#pragma unroll
        for (int m = 0; m < 4; ++m) {
            const float4 v = na[m];
#pragma unroll
            for (int n = 0; n < 4; ++n) {
                // rows m*32.. use acc[2m] (regs 0-3 of rows +0..3) and acc[2m+1]
                s1a += fsqrt(fmaxf(fmaf(-2.f, acc[2*m][n][0], v.x + nb[n]), 0.f));
                s1b += fsqrt(fmaxf(fmaf(-2.f, acc[2*m][n][1], v.y + nb[n]), 0.f));
                s1c += fsqrt(fmaxf(fmaf(-2.f, acc[2*m][n][2], v.z + nb[n]), 0.f));
                s1d += fsqrt(fmaxf(fmaf(-2.f, acc[2*m][n][3], v.w + nb[n]), 0.f));
            }
        }
        // odd m-halves: rows m*32+16..: need na at +16 -> reload pattern below
    }
    // NOTE: na[] covers only every other 16-row group with *32 stride; handle
    // all 8 m-groups correctly: redo with direct loads for the general case.
    if (!diag) {
#pragma unroll
        for (int m = 1; m < 8; m += 2) {
            const float4 v = *reinterpret_cast<const float4*>(sqA + m * 16);
#pragma unroll
            for (int n = 0; n < 4; ++n) {
                s1a += fsqrt(fmaxf(fmaf(-2.f, acc[m][n][0], v.x + nb[n]), 0.f));
                s1b += fsqrt(fmaxf(fmaf(-2.f, acc[m][n][1], v.y + nb[n]), 0.f));
                s1c += fsqrt(fmaxf(fmaf(-2.f, acc[m][n][2], v.z + nb[n]), 0.f));
                s1d += fsqrt(fmaxf(fmaf(-2.f, acc[m][n][3], v.w + nb[n]), 0.f));
            }
        }
    } else {
#pragma unroll
        for (int m = 0; m < 8; ++m) {
            const float4 v = *reinterpret_cast<const float4*>(sqA + m * 16);
            const float nav[4] = {v.x, v.y, v.z, v.w};
#pragma unroll
            for (int n = 0; n < 4; ++n) {
                const int col = wc4 * 64 + n * 16 + (lane & 15);
#pragma unroll
                for (int r = 0; r < 4; ++r) {
                    const int row = wr2 * 128 + m * 16 + (lane >> 4) * 4 + r;
                    float d = fmaxf(fmaf(-2.f, acc[m][n][r], nav[r] + nb[n]), 0.f);
                    if (row == col) d = 0.f;      // exact-0 diagonal like ref
                    s1a += fsqrt(d);
                }
            }
        }
    }
    float s1 = (s1a + s1b) + (s1c + s1d);
#pragma unroll
    for (int off = 1; off < 64; off <<= 1) s1 += __shfl_xor(s1, off);
    const double w = diag ? 1.0 : 2.0;
    if (lane == 0) rr[wv] = (double)s1 * w;
    __syncthreads();
    if (tid == 0) {
        double t1 = 0.0;
#pragma unroll
        for (int i = 0; i < 8; ++i) t1 += rr[i];
        partials[f] = t1;
    }
#undef STAGE
#undef COMPUTE
}

// ---- finalize: S1 reduce + closed-form S2 (deterministic fp64) ----
__global__ __launch_bounds__(256)
void ph_finalize(const double* __restrict__ partials, const float* __restrict__ sq,
                 const float* __restrict__ cs_part, float* __restrict__ out)
{
    __shared__ double r1[256], r2[256], r3[128];
    const int tid = threadIdx.x;
    double s1 = 0.0;
    for (int i = tid; i < NBLK; i += 256) s1 += partials[i];
    double sn = 0.0;
    for (int k = 0; k < NPTS / 256; ++k) sn += (double)sq[tid + k * 256];
    r1[tid] = s1; r2[tid] = sn;
    if (tid < DIM) {                       // column sum over 256 prep blocks
        double c = 0.0;
        for (int b = 0; b < NPREP; ++b) c += (double)cs_part[b * DIM + tid];
        r3[tid] = c * c;                   // squared component
    }
    __syncthreads();
    for (int off = 128; off > 0; off >>= 1) {
        if (tid < off) {
            r1[tid] += r1[tid + off];
            r2[tid] += r2[tid + off];
            if (off >= 2 && tid < (off >> 1) && off <= 128) {}
        }
        __syncthreads();
    }
    // reduce r3 (128 entries)
    for (int off = 64; off > 0; off >>= 1) {
        if (tid < off) r3[tid] += r3[tid + off];
        __syncthreads();
    }
    if (tid == 0) {
        const double M    = (double)NPTS * (double)NPTS;
        const double S1   = r1[0];
        const double S2   = 2.0 * (double)NPTS * r2[0] - 2.0 * r3[0];
        const double mean = S1 / M;
        double var = (S2 - S1 * S1 / M) / (M - 1.0);
        if (var < 0.0) var = 0.0;
        out[0] = (float)(sqrt(var) / (mean + 1e-8));
    }
}

// ---------------- fp32 fallback (only if ws too small) ----------------
#define LSTR 132
__global__ __launch_bounds__(256)
void ph_pair_kernel(const float* __restrict__ x, double* __restrict__ partials)
{
    const int bi  = blockIdx.y;
    const int bj  = blockIdx.x;
    const int tid = threadIdx.x;
    const int flat = bi * NTILES + bj;
    if (bj < bi) {
        if (tid == 0) { partials[2*flat] = 0.0; partials[2*flat+1] = 0.0; }
        return;
    }
    __shared__ __align__(16) float As[128 * LSTR];
    __shared__ __align__(16) float Bs[128 * LSTR];
    __shared__ float  nA[128];
    __shared__ float  nB[128];
    __shared__ double red1[256];
    __shared__ double red2[256];
    const float* Ab = x + (size_t)bi * 128 * DIM;
    const float* Bb = x + (size_t)bj * 128 * DIM;
#pragma unroll
    for (int it = 0; it < 16; ++it) {
        const int e   = (tid + it * 256) * 4;
        const int row = e >> 7;
        const int k   = e & 127;
        float4 va = *reinterpret_cast<const float4*>(Ab + e);
        As[(k+0)*LSTR + row] = va.x; As[(k+1)*LSTR + row] = va.y;
        As[(k+2)*LSTR + row] = va.z; As[(k+3)*LSTR + row] = va.w;
        float4 vb = *reinterpret_cast<const float4*>(Bb + e);
        Bs[(k+0)*LSTR + row] = vb.x; Bs[(k+1)*LSTR + row] = vb.y;
        Bs[(k+2)*LSTR + row] = vb.z; Bs[(k+3)*LSTR + row] = vb.w;
    }
    __syncthreads();
    if (tid < 128) {
        float s = 0.f;
#pragma unroll 8
        for (int k = 0; k < DIM; ++k) { float v = As[k*LSTR + tid]; s = fmaf(v, v, s); }
        nA[tid] = s;
    } else {
        const int r = tid - 128;
        float s = 0.f;
#pragma unroll 8
        for (int k = 0; k < DIM; ++k) { float v = Bs[k*LSTR + r]; s = fmaf(v, v, s); }
        nB[r] = s;
    }
    __syncthreads();
    const int tx = tid & 15, ty = tid >> 4;
    const int ra = ty * 8, cb = tx * 8;
    float acc[8][8];
#pragma unroll
    for (int r = 0; r < 8; ++r)
#pragma unroll
        for (int c = 0; c < 8; ++c) acc[r][c] = 0.f;
#pragma unroll 4
    for (int k = 0; k < DIM; ++k) {
        const float4 a0 = *reinterpret_cast<const float4*>(&As[k*LSTR + ra]);
        const float4 a1 = *reinterpret_cast<const float4*>(&As[k*LSTR + ra + 4]);
        const float4 b0 = *reinterpret_cast<const float4*>(&Bs[k*LSTR + cb]);
        const float4 b1 = *reinterpret_cast<const float4*>(&Bs[k*LSTR + cb + 4]);
        const float a[8] = {a0.x,a0.y,a0.z,a0.w,a1.x,a1.y,a1.z,a1.w};
        const float b[8] = {b0.x,b0.y,b0.z,b0.w,b1.x,b1.y,b1.z,b1.w};
#pragma unroll
        for (int r = 0; r < 8; ++r)
#pragma unroll
            for (int c = 0; c < 8; ++c)
                acc[r][c] = fmaf(a[r], b[c], acc[r][c]);
    }
    double s1 = 0.0, s2 = 0.0;
    const int gi0 = bi*128 + ra, gj0 = bj*128 + cb;
#pragma unroll
    for (int r = 0; r < 8; ++r) {
#pragma unroll
        for (int c = 0; c < 8; ++c) {
            float d2 = nA[ra+r] + nB[cb+c] - 2.0f * acc[r][c];
            d2 = fmaxf(d2, 0.0f);
            if (gi0 + r == gj0 + c) d2 = 0.0f;
            s1 += (double)sqrtf(d2);
            s2 += (double)d2;
        }
    }
    const double w = (bi == bj) ? 1.0 : 2.0;
    s1 *= w; s2 *= w;
    red1[tid] = s1; red2[tid] = s2;
    __syncthreads();
    for (int off = 128; off > 0; off >>= 1) {
        if (tid < off) { red1[tid] += red1[tid+off]; red2[tid] += red2[tid+off]; }
        __syncthreads();
    }
    if (tid == 0) { partials[2*flat] = red1[0]; partials[2*flat+1] = red2[0]; }
}

__global__ __launch_bounds__(256)
void ph_finalize_sq(const double* __restrict__ partials, float* __restrict__ out)
{
    __shared__ double r1[256], r2[256];
    const int tid = threadIdx.x;
    double s1 = 0.0, s2 = 0.0;
    for (int i = tid; i < NTOTSQ; i += 256) { s1 += partials[2*i]; s2 += partials[2*i+1]; }
    r1[tid] = s1; r2[tid] = s2;
    __syncthreads();
    for (int off = 128; off > 0; off >>= 1) {
        if (tid < off) { r1[tid] += r1[tid+off]; r2[tid] += r2[tid+off]; }
        __syncthreads();
    }
    if (tid == 0) {
        const double M    = (double)NPTS * (double)NPTS;
        const double mean = r1[0] / M;
        double var = (r2[0] - r1[0]*r1[0]/M) / (M - 1.0);
        if (var < 0.0) var = 0.0;
        out[0] = (float)(sqrt(var) / (mean + 1e-8));
    }
}

extern "C" void kernel_launch(void* const* d_in, const int* in_sizes, int n_in,
                              void* d_out, int out_size, void* d_ws, size_t ws_size,
                              hipStream_t stream)
{
    const float* x = (const float*)d_in[0];   // [8192, 128] fp32
    float* out     = (float*)d_out;

    // ws layout: xb bf16 (2MB) | sq (32KB) | cs_part (128KB) | partials (528*8)
    const size_t XB_OFF = 0;
    const size_t SQ_OFF = (size_t)NPTS * DIM * sizeof(ushort);   // 2 MB
    const size_t CS_OFF = SQ_OFF + NPTS * sizeof(float);
    const size_t PT_OFF = CS_OFF + (size_t)NPREP * DIM * sizeof(float);
    const size_t NEEDED = PT_OFF + (size_t)NBLK * sizeof(double);

    if (ws_size >= NEEDED) {
        ushort* xb       = (ushort*)((char*)d_ws + XB_OFF);
        float*  sq       = (float*) ((char*)d_ws + SQ_OFF);
        float*  cs_part  = (float*) ((char*)d_ws + CS_OFF);
        double* partials = (double*)((char*)d_ws + PT_OFF);

        ph_prep<<<NPREP, 256, 0, stream>>>(x, xb, sq, cs_part);
        ph_gram<<<NBLK, 512, 0, stream>>>(xb, sq, partials);
        ph_finalize<<<1, 256, 0, stream>>>(partials, sq, cs_part, out);
    } else {
        double* partials = (double*)d_ws;
        ph_pair_kernel<<<dim3(NTILES, NTILES), 256, 0, stream>>>(x, partials);
        ph_finalize_sq<<<1, 256, 0, stream>>>(partials, out);
    }
}

// Round 9
// 38.354 us; speedup vs baseline: 1.0356x; 1.0356x over previous
//
#include <hip/hip_runtime.h>
#include <hip/hip_bf16.h>
#include <math.h>

// PersistentHomology: out = std(dist, ddof=1) / (mean(dist) + 1e-8) over the
// 8192x8192 Euclidean distance matrix of 8192 fp32 points, D=128.
// S1 = sum(dist) via bf16-MFMA Gram tiles (upper-triangle, 256^2 blocks).
// S2 = sum(dist^2) closed form: 2N*sum|x_i|^2 - 2*|sum_i x_i|^2 (exact fp64).
// Round 9: r7's verified 256^2 double-buffered swizzled structure, but
// 16 waves x 64x64 wave-tile (acc=64 VGPR, launch_bounds cap 128) ->
// 16 waves/CU (4/SIMD) instead of r7's VGPR-capped 8 -> drains overlap.

#define NPTS   8192
#define DIM    128
#define BT     256                            // block tile
#define NT2    (NPTS / BT)                    // 32 tiles per side
#define NBLK   (NT2 * (NT2 + 1) / 2)          // 528 upper-tri blocks
#define NPREP  (NPTS / 32)                    // 256 prep blocks
#define NTILES (NPTS / 128)                   // fp32 fallback path
#define NTOTSQ (NTILES * NTILES)

typedef __attribute__((ext_vector_type(8))) short short8;   // 8 bf16
typedef __attribute__((ext_vector_type(4))) float f32x4;    // MFMA accumulator

typedef const __attribute__((address_space(1))) void* gas_ptr;
typedef __attribute__((address_space(3))) void* las_ptr;

__device__ __forceinline__ void gload16(const void* g, void* l) {
    // DMA 16B/lane global->LDS; LDS dest = wave-uniform base + lane*16
    __builtin_amdgcn_global_load_lds((gas_ptr)g, (las_ptr)l, 16, 0, 0);
}
__device__ __forceinline__ float fsqrt(float x) {
    return __builtin_amdgcn_sqrtf(x);        // v_sqrt_f32
}

// ---- prep: fp32 -> bf16, fp32 norms, per-block fp32 column-sum partials ----
__global__ __launch_bounds__(256)
void ph_prep(const float* __restrict__ x, ushort* __restrict__ xb,
             float* __restrict__ sq, float* __restrict__ cs_part)
{
    __shared__ float xs[32][129];                  // padded: conflict-free col reads
    const int tid = threadIdx.x;
    const int rw  = tid >> 3;                      // 0..31 row-in-block
    const int row = blockIdx.x * 32 + rw;
    const int seg = tid & 7;                       // 16 elems per thread
    const float4* p = reinterpret_cast<const float4*>(x + (size_t)row * DIM + seg * 16);
    float v[16];
    {
        float4 a = p[0], b = p[1], c = p[2], d = p[3];
        v[0]=a.x; v[1]=a.y; v[2]=a.z; v[3]=a.w;  v[4]=b.x; v[5]=b.y; v[6]=b.z; v[7]=b.w;
        v[8]=c.x; v[9]=c.y; v[10]=c.z; v[11]=c.w; v[12]=d.x; v[13]=d.y; v[14]=d.z; v[15]=d.w;
    }
    float s = 0.f;
    ushort h[16];
#pragma unroll
    for (int j = 0; j < 16; ++j) {
        __hip_bfloat16 hb = __float2bfloat16(v[j]);
        h[j] = *reinterpret_cast<ushort*>(&hb);
        s = fmaf(v[j], v[j], s);
        xs[rw][seg * 16 + j] = v[j];
    }
    short8 o0, o1;
#pragma unroll
    for (int j = 0; j < 8; ++j) { o0[j] = (short)h[j]; o1[j] = (short)h[j+8]; }
    short8* dst = reinterpret_cast<short8*>(xb + (size_t)row * DIM + seg * 16);
    dst[0] = o0; dst[1] = o1;
    s += __shfl_xor(s, 1); s += __shfl_xor(s, 2); s += __shfl_xor(s, 4);
    if (seg == 0) sq[row] = s;
    __syncthreads();
    if (tid < DIM) {                               // column sums over 32 rows
        float c = 0.f;
#pragma unroll 8
        for (int r = 0; r < 32; ++r) c += xs[r][tid];
        cs_part[blockIdx.x * DIM + tid] = c;
    }
}

// ---- main: 256^2 tile, 16 waves x 64x64, K-half double-buffer, S1 only ----
// LDS half-buffers: 256 rows x 128B, swizzled: phys = row*128 + (kb ^ ((row&7)<<4))
// Stage writes linear (gload_lds); inverse swizzle applied on the GLOBAL source.
__global__ __launch_bounds__(1024, 4)
void ph_gram(const ushort* __restrict__ xb, const float* __restrict__ sq,
             double* __restrict__ partials)
{
    const int f   = blockIdx.x;          // 0..NBLK-1
    const int tid = threadIdx.x;

    // decode flat -> (bi, bj), bi <= bj ; T(r) = r*32 - r*(r-1)/2
    int bi = (int)((65.0f - fsqrt((float)(4225 - 8 * f))) * 0.5f);
    while ((bi + 1) * 32 - ((bi + 1) * bi) / 2 <= f) ++bi;
    while (bi * 32 - (bi * (bi - 1)) / 2 > f) --bi;
    const int bj = bi + (f - (bi * 32 - (bi * (bi - 1)) / 2));

    __shared__ ushort A0[BT * 64], B0[BT * 64];   // 32 KB each (K-half 0)
    __shared__ ushort A1[BT * 64], B1[BT * 64];   // 32 KB each (K-half 1)
    __shared__ double rr[32];

    const int lane = tid & 63;
    const int wv   = tid >> 6;           // wave 0..15
    const int wr   = wv >> 2;            // 0..3 -> row base *64
    const int wc   = wv & 3;             // 0..3 -> col base *64

    const char* gA = (const char*)(xb + (size_t)bi * BT * DIM);
    const char* gB = (const char*)(xb + (size_t)bj * BT * DIM);

    // staging: waves 0-7 stage A (32 chunks of 1KB), waves 8-15 stage B
    const bool  stA  = wv < 8;
    const char* gsrc = stA ? gA : gB;
    const int   c0   = (wv & 7) * 4;           // 4 chunks per wave
    const int   srow = lane >> 3;              // 0..7 within chunk
    const int   skb  = (lane & 7) * 16;        // 16B slot within 128B row

#define STAGE(h, dA, dB)                                                      \
    {                                                                         \
        char* dst_ = stA ? (char*)(dA) : (char*)(dB);                         \
        _Pragma("unroll")                                                     \
        for (int c = 0; c < 4; ++c) {                                         \
            const int chunk = c0 + c;                                         \
            const int row   = chunk * 8 + srow;                               \
            const size_t go = (size_t)row * 256 + (h) * 128                   \
                              + (skb ^ ((row & 7) << 4));                     \
            gload16(gsrc + go, dst_ + chunk * 1024);                          \
        }                                                                     \
    }

    f32x4 acc[4][4];
#pragma unroll
    for (int m = 0; m < 4; ++m)
#pragma unroll
        for (int n = 0; n < 4; ++n) acc[m][n] = (f32x4){0.f, 0.f, 0.f, 0.f};

#define COMPUTE(dA, dB)                                                       \
    {                                                                         \
        _Pragma("unroll")                                                     \
        for (int ks = 0; ks < 2; ++ks) {                                      \
            const int kb = ks * 64 + (lane >> 4) * 16;                        \
            short8 af[4], bfr[4];                                             \
            _Pragma("unroll")                                                 \
            for (int m = 0; m < 4; ++m) {                                     \
                const int row = wr * 64 + m * 16 + (lane & 15);               \
                af[m] = *reinterpret_cast<const short8*>(                     \
                    (const char*)(dA) + row * 128 + (kb ^ ((row & 7) << 4))); \
            }                                                                 \
            _Pragma("unroll")                                                 \
            for (int n = 0; n < 4; ++n) {                                     \
                const int col = wc * 64 + n * 16 + (lane & 15);               \
                bfr[n] = *reinterpret_cast<const short8*>(                    \
                    (const char*)(dB) + col * 128 + (kb ^ ((col & 7) << 4))); \
            }                                                                 \
            __builtin_amdgcn_s_setprio(1);                                    \
            _Pragma("unroll")                                                 \
            for (int m = 0; m < 4; ++m)                                       \
                _Pragma("unroll")                                             \
                for (int n = 0; n < 4; ++n)                                   \
                    acc[m][n] = __builtin_amdgcn_mfma_f32_16x16x32_bf16(      \
                        af[m], bfr[n], acc[m][n], 0, 0, 0);                   \
            __builtin_amdgcn_s_setprio(0);                                    \
        }                                                                     \
    }

    STAGE(0, A0, B0);
    __syncthreads();      // half 0 ready (drains vmcnt)
    STAGE(1, A1, B1);     // half 1 flies under half-0 compute
    COMPUTE(A0, B0);
    __syncthreads();      // half 1 ready (loads landed under compute)
    COMPUTE(A1, B1);

    // ---- epilogue: S1 only (S2 closed-form), norms from L1/L2 now ----
    const float* sqA = sq + bi * BT + wr * 64 + (lane >> 4) * 4;
    const float* sqB = sq + bj * BT + wc * 64 + (lane & 15);
    float nb[4];
#pragma unroll
    for (int n = 0; n < 4; ++n) nb[n] = sqB[n * 16];

    float s1a = 0.f, s1b = 0.f, s1c = 0.f, s1d = 0.f;
    const bool diag = (bi == bj);
    if (!diag) {
#pragma unroll
        for (int m = 0; m < 4; ++m) {
            const float4 v = *reinterpret_cast<const float4*>(sqA + m * 16);
#pragma unroll
            for (int n = 0; n < 4; ++n) {
                s1a += fsqrt(fmaxf(fmaf(-2.f, acc[m][n][0], v.x + nb[n]), 0.f));
                s1b += fsqrt(fmaxf(fmaf(-2.f, acc[m][n][1], v.y + nb[n]), 0.f));
                s1c += fsqrt(fmaxf(fmaf(-2.f, acc[m][n][2], v.z + nb[n]), 0.f));
                s1d += fsqrt(fmaxf(fmaf(-2.f, acc[m][n][3], v.w + nb[n]), 0.f));
            }
        }
    } else {
#pragma unroll
        for (int m = 0; m < 4; ++m) {
            const float4 v = *reinterpret_cast<const float4*>(sqA + m * 16);
            const float nav[4] = {v.x, v.y, v.z, v.w};
#pragma unroll
            for (int n = 0; n < 4; ++n) {
                const int col = wc * 64 + n * 16 + (lane & 15);
#pragma unroll
                for (int r = 0; r < 4; ++r) {
                    const int row = wr * 64 + m * 16 + (lane >> 4) * 4 + r;
                    float d = fmaxf(fmaf(-2.f, acc[m][n][r], nav[r] + nb[n]), 0.f);
                    if (row == col) d = 0.f;      // exact-0 diagonal like ref
                    s1a += fsqrt(d);
                }
            }
        }
    }
    float s1 = (s1a + s1b) + (s1c + s1d);
#pragma unroll
    for (int off = 1; off < 64; off <<= 1) s1 += __shfl_xor(s1, off);
    const double w = diag ? 1.0 : 2.0;
    if (lane == 0) rr[wv] = (double)s1 * w;
    __syncthreads();
    if (tid == 0) {
        double t1 = 0.0;
#pragma unroll
        for (int i = 0; i < 16; ++i) t1 += rr[i];
        partials[f] = t1;
    }
#undef STAGE
#undef COMPUTE
}

// ---- finalize: S1 reduce + closed-form S2 (deterministic fp64) ----
__global__ __launch_bounds__(256)
void ph_finalize(const double* __restrict__ partials, const float* __restrict__ sq,
                 const float* __restrict__ cs_part, float* __restrict__ out)
{
    __shared__ double r1[256], r2[256], r3[128];
    const int tid = threadIdx.x;
    double s1 = 0.0;
    for (int i = tid; i < NBLK; i += 256) s1 += partials[i];
    double sn = 0.0;
    for (int k = 0; k < NPTS / 256; ++k) sn += (double)sq[tid + k * 256];
    r1[tid] = s1; r2[tid] = sn;
    if (tid < DIM) {                       // column sum over 256 prep blocks
        double c = 0.0;
        for (int b = 0; b < NPREP; ++b) c += (double)cs_part[b * DIM + tid];
        r3[tid] = c * c;                   // squared component
    }
    __syncthreads();
    for (int off = 128; off > 0; off >>= 1) {
        if (tid < off) { r1[tid] += r1[tid + off]; r2[tid] += r2[tid + off]; }
        __syncthreads();
    }
    for (int off = 64; off > 0; off >>= 1) {
        if (tid < off) r3[tid] += r3[tid + off];
        __syncthreads();
    }
    if (tid == 0) {
        const double M    = (double)NPTS * (double)NPTS;
        const double S1   = r1[0];
        const double S2   = 2.0 * (double)NPTS * r2[0] - 2.0 * r3[0];
        const double mean = S1 / M;
        double var = (S2 - S1 * S1 / M) / (M - 1.0);
        if (var < 0.0) var = 0.0;
        out[0] = (float)(sqrt(var) / (mean + 1e-8));
    }
}

// ---------------- fp32 fallback (only if ws too small) ----------------
#define LSTR 132
__global__ __launch_bounds__(256)
void ph_pair_kernel(const float* __restrict__ x, double* __restrict__ partials)
{
    const int bi  = blockIdx.y;
    const int bj  = blockIdx.x;
    const int tid = threadIdx.x;
    const int flat = bi * NTILES + bj;
    if (bj < bi) {
        if (tid == 0) { partials[2*flat] = 0.0; partials[2*flat+1] = 0.0; }
        return;
    }
    __shared__ __align__(16) float As[128 * LSTR];
    __shared__ __align__(16) float Bs[128 * LSTR];
    __shared__ float  nA[128];
    __shared__ float  nB[128];
    __shared__ double red1[256];
    __shared__ double red2[256];
    const float* Ab = x + (size_t)bi * 128 * DIM;
    const float* Bb = x + (size_t)bj * 128 * DIM;
#pragma unroll
    for (int it = 0; it < 16; ++it) {
        const int e   = (tid + it * 256) * 4;
        const int row = e >> 7;
        const int k   = e & 127;
        float4 va = *reinterpret_cast<const float4*>(Ab + e);
        As[(k+0)*LSTR + row] = va.x; As[(k+1)*LSTR + row] = va.y;
        As[(k+2)*LSTR + row] = va.z; As[(k+3)*LSTR + row] = va.w;
        float4 vb = *reinterpret_cast<const float4*>(Bb + e);
        Bs[(k+0)*LSTR + row] = vb.x; Bs[(k+1)*LSTR + row] = vb.y;
        Bs[(k+2)*LSTR + row] = vb.z; Bs[(k+3)*LSTR + row] = vb.w;
    }
    __syncthreads();
    if (tid < 128) {
        float s = 0.f;
#pragma unroll 8
        for (int k = 0; k < DIM; ++k) { float v = As[k*LSTR + tid]; s = fmaf(v, v, s); }
        nA[tid] = s;
    } else {
        const int r = tid - 128;
        float s = 0.f;
#pragma unroll 8
        for (int k = 0; k < DIM; ++k) { float v = Bs[k*LSTR + r]; s = fmaf(v, v, s); }
        nB[r] = s;
    }
    __syncthreads();
    const int tx = tid & 15, ty = tid >> 4;
    const int ra = ty * 8, cb = tx * 8;
    float acc[8][8];
#pragma unroll
    for (int r = 0; r < 8; ++r)
#pragma unroll
        for (int c = 0; c < 8; ++c) acc[r][c] = 0.f;
#pragma unroll 4
    for (int k = 0; k < DIM; ++k) {
        const float4 a0 = *reinterpret_cast<const float4*>(&As[k*LSTR + ra]);
        const float4 a1 = *reinterpret_cast<const float4*>(&As[k*LSTR + ra + 4]);
        const float4 b0 = *reinterpret_cast<const float4*>(&Bs[k*LSTR + cb]);
        const float4 b1 = *reinterpret_cast<const float4*>(&Bs[k*LSTR + cb + 4]);
        const float a[8] = {a0.x,a0.y,a0.z,a0.w,a1.x,a1.y,a1.z,a1.w};
        const float b[8] = {b0.x,b0.y,b0.z,b0.w,b1.x,b1.y,b1.z,b1.w};
#pragma unroll
        for (int r = 0; r < 8; ++r)
#pragma unroll
            for (int c = 0; c < 8; ++c)
                acc[r][c] = fmaf(a[r], b[c], acc[r][c]);
    }
    double s1 = 0.0, s2 = 0.0;
    const int gi0 = bi*128 + ra, gj0 = bj*128 + cb;
#pragma unroll
    for (int r = 0; r < 8; ++r) {
#pragma unroll
        for (int c = 0; c < 8; ++c) {
            float d2 = nA[ra+r] + nB[cb+c] - 2.0f * acc[r][c];
            d2 = fmaxf(d2, 0.0f);
            if (gi0 + r == gj0 + c) d2 = 0.0f;
            s1 += (double)sqrtf(d2);
            s2 += (double)d2;
        }
    }
    const double w = (bi == bj) ? 1.0 : 2.0;
    s1 *= w; s2 *= w;
    red1[tid] = s1; red2[tid] = s2;
    __syncthreads();
    for (int off = 128; off > 0; off >>= 1) {
        if (tid < off) { red1[tid] += red1[tid+off]; red2[tid] += red2[tid+off]; }
        __syncthreads();
    }
    if (tid == 0) { partials[2*flat] = red1[0]; partials[2*flat+1] = red2[0]; }
}

__global__ __launch_bounds__(256)
void ph_finalize_sq(const double* __restrict__ partials, float* __restrict__ out)
{
    __shared__ double r1[256], r2[256];
    const int tid = threadIdx.x;
    double s1 = 0.0, s2 = 0.0;
    for (int i = tid; i < NTOTSQ; i += 256) { s1 += partials[2*i]; s2 += partials[2*i+1]; }
    r1[tid] = s1; r2[tid] = s2;
    __syncthreads();
    for (int off = 128; off > 0; off >>= 1) {
        if (tid < off) { r1[tid] += r1[tid+off]; r2[tid] += r2[tid+off]; }
        __syncthreads();
    }
    if (tid == 0) {
        const double M    = (double)NPTS * (double)NPTS;
        const double mean = r1[0] / M;
        double var = (r2[0] - r1[0]*r1[0]/M) / (M - 1.0);
        if (var < 0.0) var = 0.0;
        out[0] = (float)(sqrt(var) / (mean + 1e-8));
    }
}

extern "C" void kernel_launch(void* const* d_in, const int* in_sizes, int n_in,
                              void* d_out, int out_size, void* d_ws, size_t ws_size,
                              hipStream_t stream)
{
    const float* x = (const float*)d_in[0];   // [8192, 128] fp32
    float* out     = (float*)d_out;

    // ws layout: xb bf16 (2MB) | sq (32KB) | cs_part (128KB) | partials (528*8)
    const size_t XB_OFF = 0;
    const size_t SQ_OFF = (size_t)NPTS * DIM * sizeof(ushort);   // 2 MB
    const size_t CS_OFF = SQ_OFF + NPTS * sizeof(float);
    const size_t PT_OFF = CS_OFF + (size_t)NPREP * DIM * sizeof(float);
    const size_t NEEDED = PT_OFF + (size_t)NBLK * sizeof(double);

    if (ws_size >= NEEDED) {
        ushort* xb       = (ushort*)((char*)d_ws + XB_OFF);
        float*  sq       = (float*) ((char*)d_ws + SQ_OFF);
        float*  cs_part  = (float*) ((char*)d_ws + CS_OFF);
        double* partials = (double*)((char*)d_ws + PT_OFF);

        ph_prep<<<NPREP, 256, 0, stream>>>(x, xb, sq, cs_part);
        ph_gram<<<NBLK, 1024, 0, stream>>>(xb, sq, partials);
        ph_finalize<<<1, 256, 0, stream>>>(partials, sq, cs_part, out);
    } else {
        double* partials = (double*)d_ws;
        ph_pair_kernel<<<dim3(NTILES, NTILES), 256, 0, stream>>>(x, partials);
        ph_finalize_sq<<<1, 256, 0, stream>>>(partials, out);
    }
}

// Round 10
// 35.468 us; speedup vs baseline: 1.1199x; 1.0814x over previous
//
#include <hip/hip_runtime.h>
#include <hip/hip_bf16.h>
#include <math.h>

// PersistentHomology: out = std(dist, ddof=1) / (mean(dist) + 1e-8) over the
// 8192x8192 Euclidean distance matrix of 8192 fp32 points, D=128.
// S1 = sum(dist) via bf16-MFMA Gram tiles (upper-triangle 128^2 blocks).
// S2 = sum(dist^2) closed form: 2N*sum|x_i|^2 - 2*|sum_i x_i|^2 (exact fp64).
// Round 10: occupancy bet. 128^2 tiles, 4 waves x 64x64 (acc=64 VGPR, cap 128),
// K-half single-buffered LDS = 33 KB -> 4 resident blocks/CU = 4 waves/SIMD.
// Cross-block TLP hides stage drains + epilogue (no intra-block prefetch).

#define NPTS   8192
#define DIM    128
#define TIL    128                            // block tile
#define NGRID  (NPTS / TIL)                   // 64 tiles per side
#define NTOT   (NGRID * (NGRID + 1) / 2)      // 2080 upper-tri blocks
#define NPREP  (NPTS / 32)                    // 256 prep blocks
#define NTILES (NPTS / 128)                   // fp32 fallback path
#define NTOTSQ (NTILES * NTILES)

typedef __attribute__((ext_vector_type(8))) short short8;   // 8 bf16
typedef __attribute__((ext_vector_type(4))) float f32x4;    // MFMA accumulator

typedef const __attribute__((address_space(1))) void* gas_ptr;
typedef __attribute__((address_space(3))) void* las_ptr;

__device__ __forceinline__ void gload16(const void* g, void* l) {
    // DMA 16B/lane global->LDS; LDS dest = wave-uniform base + lane*16
    __builtin_amdgcn_global_load_lds((gas_ptr)g, (las_ptr)l, 16, 0, 0);
}
__device__ __forceinline__ float fsqrt(float x) {
    return __builtin_amdgcn_sqrtf(x);        // v_sqrt_f32
}

// ---- prep: fp32 -> bf16, fp32 norms, per-block fp32 column-sum partials ----
__global__ __launch_bounds__(256)
void ph_prep(const float* __restrict__ x, ushort* __restrict__ xb,
             float* __restrict__ sq, float* __restrict__ cs_part)
{
    __shared__ float xs[32][129];                  // padded: conflict-free col reads
    const int tid = threadIdx.x;
    const int rw  = tid >> 3;                      // 0..31 row-in-block
    const int row = blockIdx.x * 32 + rw;
    const int seg = tid & 7;                       // 16 elems per thread
    const float4* p = reinterpret_cast<const float4*>(x + (size_t)row * DIM + seg * 16);
    float v[16];
    {
        float4 a = p[0], b = p[1], c = p[2], d = p[3];
        v[0]=a.x; v[1]=a.y; v[2]=a.z; v[3]=a.w;  v[4]=b.x; v[5]=b.y; v[6]=b.z; v[7]=b.w;
        v[8]=c.x; v[9]=c.y; v[10]=c.z; v[11]=c.w; v[12]=d.x; v[13]=d.y; v[14]=d.z; v[15]=d.w;
    }
    float s = 0.f;
    ushort h[16];
#pragma unroll
    for (int j = 0; j < 16; ++j) {
        __hip_bfloat16 hb = __float2bfloat16(v[j]);
        h[j] = *reinterpret_cast<ushort*>(&hb);
        s = fmaf(v[j], v[j], s);
        xs[rw][seg * 16 + j] = v[j];
    }
    short8 o0, o1;
#pragma unroll
    for (int j = 0; j < 8; ++j) { o0[j] = (short)h[j]; o1[j] = (short)h[j+8]; }
    short8* dst = reinterpret_cast<short8*>(xb + (size_t)row * DIM + seg * 16);
    dst[0] = o0; dst[1] = o1;
    s += __shfl_xor(s, 1); s += __shfl_xor(s, 2); s += __shfl_xor(s, 4);
    if (seg == 0) sq[row] = s;
    __syncthreads();
    if (tid < DIM) {                               // column sums over 32 rows
        float c = 0.f;
#pragma unroll 8
        for (int r = 0; r < 32; ++r) c += xs[r][tid];
        cs_part[blockIdx.x * DIM + tid] = c;
    }
}

// ---- main: 128^2 tile, 4 waves x 64x64, K-half single-buffer, 4 blocks/CU ----
// LDS K-half buffers: 128 rows x 128B, swizzled: phys = row*128 + (kb ^ ((row&7)<<4))
// Stage writes linear (gload_lds); inverse swizzle applied on the GLOBAL source.
__global__ __launch_bounds__(256, 4)
void ph_gram(const ushort* __restrict__ xb, const float* __restrict__ sq,
             double* __restrict__ partials)
{
    const int f   = blockIdx.x;          // 0..NTOT-1
    const int tid = threadIdx.x;

    // decode flat -> (bi, bj), bi <= bj ; T(r) = r*64 - r*(r-1)/2  (r3-proven)
    int bi = (int)((129.0f - fsqrt((float)(16641 - 8 * f))) * 0.5f);
    while ((bi + 1) * 64 - ((bi + 1) * bi) / 2 <= f) ++bi;
    while (bi * 64 - (bi * (bi - 1)) / 2 > f) --bi;
    const int bj = bi + (f - (bi * 64 - (bi * (bi - 1)) / 2));

    __shared__ ushort Ah[TIL * 64];      // 16 KB (one K-half of A)
    __shared__ ushort Bh[TIL * 64];      // 16 KB (one K-half of B)
    __shared__ double rr[4];

    const int lane = tid & 63;
    const int wv   = tid >> 6;           // wave 0..3
    const int wr   = wv >> 1;            // 0..1 -> row base *64
    const int wc   = wv & 1;             // 0..1 -> col base *64

    const char* gA = (const char*)(xb + (size_t)bi * TIL * DIM);
    const char* gB = (const char*)(xb + (size_t)bj * TIL * DIM);

    // staging: each wave stages 4 A-chunks + 4 B-chunks of 1KB (8 rows each)
    const int srow = lane >> 3;                    // 0..7 within chunk
    const int skb  = (lane & 7) * 16;              // 16B slot within 128B row

#define STAGE(h)                                                              \
    {                                                                         \
        _Pragma("unroll")                                                     \
        for (int c = 0; c < 4; ++c) {                                         \
            const int chunk = wv * 4 + c;                                     \
            const int row   = chunk * 8 + srow;                               \
            const size_t go = (size_t)row * 256 + (h) * 128                   \
                              + (skb ^ ((row & 7) << 4));                     \
            gload16(gA + go, (char*)Ah + chunk * 1024);                       \
            gload16(gB + go, (char*)Bh + chunk * 1024);                       \
        }                                                                     \
    }

    f32x4 acc[4][4];
#pragma unroll
    for (int m = 0; m < 4; ++m)
#pragma unroll
        for (int n = 0; n < 4; ++n) acc[m][n] = (f32x4){0.f, 0.f, 0.f, 0.f};

#define COMPUTE()                                                             \
    {                                                                         \
        _Pragma("unroll")                                                     \
        for (int ks = 0; ks < 2; ++ks) {                                      \
            const int kb = ks * 64 + (lane >> 4) * 16;                        \
            short8 af[4], bfr[4];                                             \
            _Pragma("unroll")                                                 \
            for (int m = 0; m < 4; ++m) {                                     \
                const int row = wr * 64 + m * 16 + (lane & 15);               \
                af[m] = *reinterpret_cast<const short8*>(                     \
                    (const char*)Ah + row * 128 + (kb ^ ((row & 7) << 4)));   \
            }                                                                 \
            _Pragma("unroll")                                                 \
            for (int n = 0; n < 4; ++n) {                                     \
                const int col = wc * 64 + n * 16 + (lane & 15);               \
                bfr[n] = *reinterpret_cast<const short8*>(                    \
                    (const char*)Bh + col * 128 + (kb ^ ((col & 7) << 4)));   \
            }                                                                 \
            __builtin_amdgcn_s_setprio(1);                                    \
            _Pragma("unroll")                                                 \
            for (int m = 0; m < 4; ++m)                                       \
                _Pragma("unroll")                                             \
                for (int n = 0; n < 4; ++n)                                   \
                    acc[m][n] = __builtin_amdgcn_mfma_f32_16x16x32_bf16(      \
                        af[m], bfr[n], acc[m][n], 0, 0, 0);                   \
            __builtin_amdgcn_s_setprio(0);                                    \
        }                                                                     \
    }

    STAGE(0);
    __syncthreads();      // h0 landed
    COMPUTE();
    __syncthreads();      // all waves done reading h0
    STAGE(1);
    __syncthreads();      // h1 landed
    COMPUTE();
    // (stalls here are covered by the 3 other resident blocks on this CU)

    // ---- epilogue: S1 only (S2 closed-form), norms from L1/L2 ----
    const float* sqA = sq + bi * TIL + wr * 64 + (lane >> 4) * 4;
    const float* sqB = sq + bj * TIL + wc * 64 + (lane & 15);
    float nb[4];
#pragma unroll
    for (int n = 0; n < 4; ++n) nb[n] = sqB[n * 16];

    float s1a = 0.f, s1b = 0.f, s1c = 0.f, s1d = 0.f;
    const bool diag = (bi == bj);
    if (!diag) {
#pragma unroll
        for (int m = 0; m < 4; ++m) {
            const float4 v = *reinterpret_cast<const float4*>(sqA + m * 16);
#pragma unroll
            for (int n = 0; n < 4; ++n) {
                s1a += fsqrt(fmaxf(fmaf(-2.f, acc[m][n][0], v.x + nb[n]), 0.f));
                s1b += fsqrt(fmaxf(fmaf(-2.f, acc[m][n][1], v.y + nb[n]), 0.f));
                s1c += fsqrt(fmaxf(fmaf(-2.f, acc[m][n][2], v.z + nb[n]), 0.f));
                s1d += fsqrt(fmaxf(fmaf(-2.f, acc[m][n][3], v.w + nb[n]), 0.f));
            }
        }
    } else {
#pragma unroll
        for (int m = 0; m < 4; ++m) {
            const float4 v = *reinterpret_cast<const float4*>(sqA + m * 16);
            const float nav[4] = {v.x, v.y, v.z, v.w};
#pragma unroll
            for (int n = 0; n < 4; ++n) {
                const int col = wc * 64 + n * 16 + (lane & 15);
#pragma unroll
                for (int r = 0; r < 4; ++r) {
                    const int row = wr * 64 + m * 16 + (lane >> 4) * 4 + r;
                    float d = fmaxf(fmaf(-2.f, acc[m][n][r], nav[r] + nb[n]), 0.f);
                    if (row == col) d = 0.f;      // exact-0 diagonal like ref
                    s1a += fsqrt(d);
                }
            }
        }
    }
    float s1 = (s1a + s1b) + (s1c + s1d);
#pragma unroll
    for (int off = 1; off < 64; off <<= 1) s1 += __shfl_xor(s1, off);
    const double w = diag ? 1.0 : 2.0;
    if (lane == 0) rr[wv] = (double)s1 * w;
    __syncthreads();
    if (tid == 0) partials[f] = (rr[0] + rr[1]) + (rr[2] + rr[3]);
#undef STAGE
#undef COMPUTE
}

// ---- finalize: S1 reduce + closed-form S2 (deterministic fp64) ----
__global__ __launch_bounds__(256)
void ph_finalize(const double* __restrict__ partials, const float* __restrict__ sq,
                 const float* __restrict__ cs_part, float* __restrict__ out)
{
    __shared__ double r1[256], r2[256], r3[128];
    const int tid = threadIdx.x;
    double s1 = 0.0;
    for (int i = tid; i < NTOT; i += 256) s1 += partials[i];
    double sn = 0.0;
    for (int k = 0; k < NPTS / 256; ++k) sn += (double)sq[tid + k * 256];
    r1[tid] = s1; r2[tid] = sn;
    if (tid < DIM) {                       // column sum over 256 prep blocks
        double c = 0.0;
        for (int b = 0; b < NPREP; ++b) c += (double)cs_part[b * DIM + tid];
        r3[tid] = c * c;                   // squared component
    }
    __syncthreads();
    for (int off = 128; off > 0; off >>= 1) {
        if (tid < off) { r1[tid] += r1[tid + off]; r2[tid] += r2[tid + off]; }
        __syncthreads();
    }
    for (int off = 64; off > 0; off >>= 1) {
        if (tid < off) r3[tid] += r3[tid + off];
        __syncthreads();
    }
    if (tid == 0) {
        const double M    = (double)NPTS * (double)NPTS;
        const double S1   = r1[0];
        const double S2   = 2.0 * (double)NPTS * r2[0] - 2.0 * r3[0];
        const double mean = S1 / M;
        double var = (S2 - S1 * S1 / M) / (M - 1.0);
        if (var < 0.0) var = 0.0;
        out[0] = (float)(sqrt(var) / (mean + 1e-8));
    }
}

// ---------------- fp32 fallback (only if ws too small) ----------------
#define LSTR 132
__global__ __launch_bounds__(256)
void ph_pair_kernel(const float* __restrict__ x, double* __restrict__ partials)
{
    const int bi  = blockIdx.y;
    const int bj  = blockIdx.x;
    const int tid = threadIdx.x;
    const int flat = bi * NTILES + bj;
    if (bj < bi) {
        if (tid == 0) { partials[2*flat] = 0.0; partials[2*flat+1] = 0.0; }
        return;
    }
    __shared__ __align__(16) float As[128 * LSTR];
    __shared__ __align__(16) float Bs[128 * LSTR];
    __shared__ float  nA[128];
    __shared__ float  nB[128];
    __shared__ double red1[256];
    __shared__ double red2[256];
    const float* Ab = x + (size_t)bi * 128 * DIM;
    const float* Bb = x + (size_t)bj * 128 * DIM;
#pragma unroll
    for (int it = 0; it < 16; ++it) {
        const int e   = (tid + it * 256) * 4;
        const int row = e >> 7;
        const int k   = e & 127;
        float4 va = *reinterpret_cast<const float4*>(Ab + e);
        As[(k+0)*LSTR + row] = va.x; As[(k+1)*LSTR + row] = va.y;
        As[(k+2)*LSTR + row] = va.z; As[(k+3)*LSTR + row] = va.w;
        float4 vb = *reinterpret_cast<const float4*>(Bb + e);
        Bs[(k+0)*LSTR + row] = vb.x; Bs[(k+1)*LSTR + row] = vb.y;
        Bs[(k+2)*LSTR + row] = vb.z; Bs[(k+3)*LSTR + row] = vb.w;
    }
    __syncthreads();
    if (tid < 128) {
        float s = 0.f;
#pragma unroll 8
        for (int k = 0; k < DIM; ++k) { float v = As[k*LSTR + tid]; s = fmaf(v, v, s); }
        nA[tid] = s;
    } else {
        const int r = tid - 128;
        float s = 0.f;
#pragma unroll 8
        for (int k = 0; k < DIM; ++k) { float v = Bs[k*LSTR + r]; s = fmaf(v, v, s); }
        nB[r] = s;
    }
    __syncthreads();
    const int tx = tid & 15, ty = tid >> 4;
    const int ra = ty * 8, cb = tx * 8;
    float acc[8][8];
#pragma unroll
    for (int r = 0; r < 8; ++r)
#pragma unroll
        for (int c = 0; c < 8; ++c) acc[r][c] = 0.f;
#pragma unroll 4
    for (int k = 0; k < DIM; ++k) {
        const float4 a0 = *reinterpret_cast<const float4*>(&As[k*LSTR + ra]);
        const float4 a1 = *reinterpret_cast<const float4*>(&As[k*LSTR + ra + 4]);
        const float4 b0 = *reinterpret_cast<const float4*>(&Bs[k*LSTR + cb]);
        const float4 b1 = *reinterpret_cast<const float4*>(&Bs[k*LSTR + cb + 4]);
        const float a[8] = {a0.x,a0.y,a0.z,a0.w,a1.x,a1.y,a1.z,a1.w};
        const float b[8] = {b0.x,b0.y,b0.z,b0.w,b1.x,b1.y,b1.z,b1.w};
#pragma unroll
        for (int r = 0; r < 8; ++r)
#pragma unroll
            for (int c = 0; c < 8; ++c)
                acc[r][c] = fmaf(a[r], b[c], acc[r][c]);
    }
    double s1 = 0.0, s2 = 0.0;
    const int gi0 = bi*128 + ra, gj0 = bj*128 + cb;
#pragma unroll
    for (int r = 0; r < 8; ++r) {
#pragma unroll
        for (int c = 0; c < 8; ++c) {
            float d2 = nA[ra+r] + nB[cb+c] - 2.0f * acc[r][c];
            d2 = fmaxf(d2, 0.0f);
            if (gi0 + r == gj0 + c) d2 = 0.0f;
            s1 += (double)sqrtf(d2);
            s2 += (double)d2;
        }
    }
    const double w = (bi == bj) ? 1.0 : 2.0;
    s1 *= w; s2 *= w;
    red1[tid] = s1; red2[tid] = s2;
    __syncthreads();
    for (int off = 128; off > 0; off >>= 1) {
        if (tid < off) { red1[tid] += red1[tid+off]; red2[tid] += red2[tid+off]; }
        __syncthreads();
    }
    if (tid == 0) { partials[2*flat] = red1[0]; partials[2*flat+1] = red2[0]; }
}

__global__ __launch_bounds__(256)
void ph_finalize_sq(const double* __restrict__ partials, float* __restrict__ out)
{
    __shared__ double r1[256], r2[256];
    const int tid = threadIdx.x;
    double s1 = 0.0, s2 = 0.0;
    for (int i = tid; i < NTOTSQ; i += 256) { s1 += partials[2*i]; s2 += partials[2*i+1]; }
    r1[tid] = s1; r2[tid] = s2;
    __syncthreads();
    for (int off = 128; off > 0; off >>= 1) {
        if (tid < off) { r1[tid] += r1[tid+off]; r2[tid] += r2[tid+off]; }
        __syncthreads();
    }
    if (tid == 0) {
        const double M    = (double)NPTS * (double)NPTS;
        const double mean = r1[0] / M;
        double var = (r2[0] - r1[0]*r1[0]/M) / (M - 1.0);
        if (var < 0.0) var = 0.0;
        out[0] = (float)(sqrt(var) / (mean + 1e-8));
    }
}

extern "C" void kernel_launch(void* const* d_in, const int* in_sizes, int n_in,
                              void* d_out, int out_size, void* d_ws, size_t ws_size,
                              hipStream_t stream)
{
    const float* x = (const float*)d_in[0];   // [8192, 128] fp32
    float* out     = (float*)d_out;

    // ws layout: xb bf16 (2MB) | sq (32KB) | cs_part (128KB) | partials
    const size_t XB_OFF = 0;
    const size_t SQ_OFF = (size_t)NPTS * DIM * sizeof(ushort);   // 2 MB
    const size_t CS_OFF = SQ_OFF + NPTS * sizeof(float);
    const size_t PT_OFF = CS_OFF + (size_t)NPREP * DIM * sizeof(float);
    const size_t NEEDED = PT_OFF + (size_t)NTOT * sizeof(double);

    if (ws_size >= NEEDED) {
        ushort* xb       = (ushort*)((char*)d_ws + XB_OFF);
        float*  sq       = (float*) ((char*)d_ws + SQ_OFF);
        float*  cs_part  = (float*) ((char*)d_ws + CS_OFF);
        double* partials = (double*)((char*)d_ws + PT_OFF);

        ph_prep<<<NPREP, 256, 0, stream>>>(x, xb, sq, cs_part);
        ph_gram<<<NTOT, 256, 0, stream>>>(xb, sq, partials);
        ph_finalize<<<1, 256, 0, stream>>>(partials, sq, cs_part, out);
    } else {
        double* partials = (double*)d_ws;
        ph_pair_kernel<<<dim3(NTILES, NTILES), 256, 0, stream>>>(x, partials);
        ph_finalize_sq<<<1, 256, 0, stream>>>(partials, out);
    }
}